// Round 1
// 367.572 us; speedup vs baseline: 1.0491x; 1.0491x over previous
//
#include <hip/hip_runtime.h>

// ShallowRBF: x(8192x2048), centers(4096x2048), beta(4096), W(1000x4096), b(1000)
// out = (exp(-beta*||x-c||) @ W^T) / rowsum + b
//
// R4: gemm1 ported to the 256^2 8-phase counted-vmcnt schedule (T2+T3+T4+T5):
// 512 thr / 8 waves (2Mx4N), BK=64, 128KB double-buffered LDS, 4 phases per
// K-tile {B-all+A-q0, A-q1, A-q2, A-q3} each = 16x mfma_16x16x32 wrapped in
// setprio(1); one half-tile staged per phase; raw s_barrier with vmcnt(4)
// only at the K-tile boundary (never 0 in steady state). LDS swizzle:
// chunk ^= (row&7) (m214-verified), linear gload_lds dest + pre-swizzled src.

#define BB 8192
#define DD 2048
#define CC 4096
#define KK 1000
#define KP 1024

typedef unsigned short u16;
typedef __bf16 bf16x8 __attribute__((ext_vector_type(8)));
typedef float f32x4 __attribute__((ext_vector_type(4)));
typedef float f32x16 __attribute__((ext_vector_type(16)));

typedef const void __attribute__((address_space(1)))* gvp_t;
typedef void __attribute__((address_space(3)))* lvp_t;

__device__ __forceinline__ u16 f2bf(float f) {
  union { float f; unsigned u; } v; v.f = f;
  return (u16)((v.u + 0x7fffu + ((v.u >> 16) & 1u)) >> 16);  // RNE
}

// ---- prep: row norms (fp32) + bf16 casts of x and centers ----
__global__ void prep_norm_cast(const float* __restrict__ x, const float* __restrict__ cen,
                               u16* __restrict__ xb, u16* __restrict__ cb,
                               float* __restrict__ x2, float* __restrict__ c2) {
  int row = blockIdx.x;
  const float* src;
  u16* dst;
  float* nrm;
  if (row < BB) {
    src = x + (size_t)row * DD; dst = xb + (size_t)row * DD; nrm = x2 + row;
  } else {
    int r = row - BB;
    src = cen + (size_t)r * DD; dst = cb + (size_t)r * DD; nrm = c2 + r;
  }
  int t = threadIdx.x;
  float s = 0.f;
#pragma unroll
  for (int m = 0; m < 2; ++m) {
    int idx = t + 256 * m;
    float4 v = reinterpret_cast<const float4*>(src)[idx];
    s += v.x * v.x + v.y * v.y + v.z * v.z + v.w * v.w;
    reinterpret_cast<ushort4*>(dst)[idx] =
        make_ushort4(f2bf(v.x), f2bf(v.y), f2bf(v.z), f2bf(v.w));
  }
#pragma unroll
  for (int off = 1; off < 64; off <<= 1) s += __shfl_xor(s, off);
  __shared__ float red[4];
  if ((t & 63) == 0) red[t >> 6] = s;
  __syncthreads();
  if (t == 0) *nrm = red[0] + red[1] + red[2] + red[3];
}

// ---- prep: W cast to bf16, padded to 1024 rows (zeros) ----
__global__ void prep_wcast(const float* __restrict__ W, u16* __restrict__ wb) {
  int row = blockIdx.x;  // 0..1023
  int t = threadIdx.x;
  ushort4* dst = reinterpret_cast<ushort4*>(wb + (size_t)row * CC);
  if (row < KK) {
    const float4* src = reinterpret_cast<const float4*>(W + (size_t)row * CC);
#pragma unroll
    for (int m = 0; m < 4; ++m) {
      float4 v = src[t + 256 * m];
      dst[t + 256 * m] = make_ushort4(f2bf(v.x), f2bf(v.y), f2bf(v.z), f2bf(v.w));
    }
  } else {
#pragma unroll
    for (int m = 0; m < 4; ++m) dst[t + 256 * m] = make_ushort4(0, 0, 0, 0);
  }
}

// ======================= GEMM1: 256x256 8-phase =======================
// LDS layout per buffer (64KB): A 256x64 bf16 (32KB) @0, B 256x64 (32KB) @32768.
// Row = 128B; logical 16B-chunk s of row r stored at phys chunk s^(r&7).
// Staging (linear dest): thread t -> row t>>3 (+64/it), phys chunk t&7, so it
// fetches logical chunk (t&7)^((t>>3)&7) from global.

#define SB0 __builtin_amdgcn_sched_barrier(0)
#define BARR __builtin_amdgcn_s_barrier()
#define LGKM0 asm volatile("s_waitcnt lgkmcnt(0)" ::: "memory")

#define ST_A(BUF, H, TILE)                                                         \
  {                                                                                \
    const u16* _s = gA0 + (size_t)((H) * 128) * DD + (TILE) * 64;                  \
    char* _d = (char*)smem + (BUF) * 65536 + (H) * 16384 + t * 16;                 \
    __builtin_amdgcn_global_load_lds((gvp_t)_s, (lvp_t)_d, 16, 0, 0);              \
    __builtin_amdgcn_global_load_lds((gvp_t)(_s + (size_t)64 * DD),                \
                                     (lvp_t)(_d + 8192), 16, 0, 0);                \
  }

#define ST_B(BUF, H, TILE)                                                         \
  {                                                                                \
    const u16* _s = gB0 + (size_t)((H) * 128) * DD + (TILE) * 64;                  \
    char* _d = (char*)smem + (BUF) * 65536 + 32768 + (H) * 16384 + t * 16;         \
    __builtin_amdgcn_global_load_lds((gvp_t)_s, (lvp_t)_d, 16, 0, 0);              \
    __builtin_amdgcn_global_load_lds((gvp_t)(_s + (size_t)64 * DD),                \
                                     (lvp_t)(_d + 8192), 16, 0, 0);                \
  }

#define READ_B(SBP)                                                                \
  _Pragma("unroll") for (int n_ = 0; n_ < 4; ++n_) {                               \
    _Pragma("unroll") for (int ks_ = 0; ks_ < 2; ++ks_) {                          \
      bfr[n_][ks_] = *(const bf16x8*)((SBP) + bRow + n_ * 2048 + cbv[ks_]);        \
    }                                                                              \
  }

#define READ_A(SAP, MQ)                                                            \
  _Pragma("unroll") for (int m_ = 0; m_ < 2; ++m_) {                               \
    _Pragma("unroll") for (int ks_ = 0; ks_ < 2; ++ks_) {                          \
      af[m_][ks_] =                                                                \
          *(const bf16x8*)((SAP) + aRow + ((MQ)*2 + m_) * 2048 + cbv[ks_]);        \
    }                                                                              \
  }

#define MFMA_Q(MQ)                                                                 \
  __builtin_amdgcn_s_setprio(1);                                                   \
  _Pragma("unroll") for (int m_ = 0; m_ < 2; ++m_) {                               \
    _Pragma("unroll") for (int n_ = 0; n_ < 4; ++n_) {                             \
      _Pragma("unroll") for (int ks_ = 0; ks_ < 2; ++ks_) {                        \
        acc[(MQ)*2 + m_][n_] = __builtin_amdgcn_mfma_f32_16x16x32_bf16(            \
            af[m_][ks_], bfr[n_][ks_], acc[(MQ)*2 + m_][n_], 0, 0, 0);             \
      }                                                                            \
    }                                                                              \
  }                                                                                \
  __builtin_amdgcn_s_setprio(0)

// Stage-slot safety: ph1 writes the idle buffer (A-halves of tile+1), ph2/ph3
// write B-regions of the current buffer whose reads (all in ph1) are consumed
// before ph1's closing barrier. Every stage is >=1 full barrier after the last
// read of its target region. vmcnt(4) at the tile boundary leaves the 2 B
// half-tiles of tile+2 in flight; guarantees tile+1 fully landed.
#define TILE_BODY(TILE, CUR, DOA, DOB, VMN)                                        \
  {                                                                                \
    const char* sA_ = (const char*)smem + (CUR) * 65536;                           \
    const char* sB_ = sA_ + 32768;                                                 \
    READ_B(sB_);                                                                   \
    READ_A(sA_, 0);                                                                \
    SB0;                                                                           \
    if (DOA) { ST_A(1 - (CUR), 0, (TILE) + 1); ST_A(1 - (CUR), 1, (TILE) + 1); }   \
    SB0; BARR; LGKM0; SB0;                                                         \
    MFMA_Q(0); SB0; BARR;                                                          \
    READ_A(sA_, 1); SB0;                                                           \
    if (DOB) { ST_B((CUR), 0, (TILE) + 2); }                                       \
    SB0; BARR; LGKM0; SB0;                                                         \
    MFMA_Q(1); SB0; BARR;                                                          \
    READ_A(sA_, 2); SB0;                                                           \
    if (DOB) { ST_B((CUR), 1, (TILE) + 2); }                                       \
    SB0; BARR; LGKM0; SB0;                                                         \
    MFMA_Q(2); SB0; BARR;                                                          \
    READ_A(sA_, 3); SB0; BARR; LGKM0; SB0;                                         \
    MFMA_Q(3);                                                                     \
    if ((VMN) == 4) { asm volatile("s_waitcnt vmcnt(4)" ::: "memory"); }           \
    else if ((VMN) == 0) { asm volatile("s_waitcnt vmcnt(0)" ::: "memory"); }      \
    SB0; BARR;                                                                     \
  }

__global__ __launch_bounds__(512, 2)
void gemm1_rbf(const u16* __restrict__ Abf, const u16* __restrict__ Bbf,
               const float* __restrict__ x2, const float* __restrict__ c2,
               const float* __restrict__ beta, u16* __restrict__ Ebf) {
  constexpr int NT = DD / 64;  // 32 K-tiles
  __shared__ __align__(16) char smem[131072];

  const int t = threadIdx.x;
  const int lane = t & 63;
  const int wave = t >> 6;
  const int wr = wave >> 2;  // 0..1: rows wr*128..
  const int wc = wave & 3;   // 0..3: cols wc*64..
  const int l15 = lane & 15;

  const int rowBase = blockIdx.y * 256;
  const int colBase = blockIdx.x * 256;

  f32x4 acc[8][4];
#pragma unroll
  for (int i = 0; i < 8; ++i)
#pragma unroll
    for (int j = 0; j < 4; ++j) acc[i][j] = 0.f;

  // staging source (pre-swizzled logical chunk)
  const int srow = t >> 3;
  const u16* gA0 = Abf + (size_t)(rowBase + srow) * DD + ((t & 7) ^ (srow & 7)) * 8;
  const u16* gB0 = Bbf + (size_t)(colBase + srow) * DD + ((t & 7) ^ (srow & 7)) * 8;

  // frag-read byte column per kstep: phys chunk = (ks*4 + l>>4) ^ (l&7)
  int cbv[2];
  cbv[0] = (((lane >> 4) & 3) ^ (lane & 7)) << 4;
  cbv[1] = ((4 + ((lane >> 4) & 3)) ^ (lane & 7)) << 4;
  const int aRow = (wr * 128 + l15) * 128;
  const int bRow = (wc * 64 + l15) * 128;

  bf16x8 bfr[4][2];
  bf16x8 af[2][2];

  // prologue: tile0 complete + tile1 B-halves in flight
  ST_A(0, 0, 0); ST_A(0, 1, 0); ST_B(0, 0, 0); ST_B(0, 1, 0);
  ST_B(1, 0, 1); ST_B(1, 1, 1);
  asm volatile("s_waitcnt vmcnt(4)" ::: "memory");
  BARR;

#pragma unroll 2
  for (int tile = 0; tile < NT - 2; ++tile) {
    TILE_BODY(tile, tile & 1, true, true, 4);
  }
  TILE_BODY(NT - 2, (NT - 2) & 1, true, false, 0);
  TILE_BODY(NT - 1, (NT - 1) & 1, false, false, -1);

  // epilogue: C/D layout (16x16): col = lane&15, row = (lane>>4)*4 + reg
  const int khi4 = (lane >> 4) * 4;
  float c2v[4], bet[4];
  int gc[4];
#pragma unroll
  for (int n = 0; n < 4; ++n) {
    gc[n] = colBase + wc * 64 + n * 16 + l15;
    c2v[n] = c2[gc[n]];
    bet[n] = beta[gc[n]];
  }
#pragma unroll
  for (int m = 0; m < 8; ++m) {
#pragma unroll
    for (int r = 0; r < 4; ++r) {
      const int grow = rowBase + wr * 128 + m * 16 + khi4 + r;
      const float x2v = x2[grow];
      u16* orow = Ebf + (size_t)grow * CC;
#pragma unroll
      for (int n = 0; n < 4; ++n) {
        float d = acc[m][n][r];
        float sq = fmaxf(x2v + c2v[n] - 2.0f * d, 0.0f);
        float e = __expf(-bet[n] * __builtin_amdgcn_sqrtf(sq));
        orow[gc[n]] = f2bf(e);
      }
    }
  }
}

// ---- rowsum: one wave per row of Ebf ----
__global__ void rowsum_k(const u16* __restrict__ Ebf, float* __restrict__ rowsum) {
  const int lane = threadIdx.x & 63;
  const int row = blockIdx.x * 4 + (threadIdx.x >> 6);
  const uint4* p = reinterpret_cast<const uint4*>(Ebf + (size_t)row * CC);
  float s = 0.f;
#pragma unroll
  for (int it = 0; it < 8; ++it) {
    uint4 v = p[lane + 64 * it];
    unsigned w[4] = {v.x, v.y, v.z, v.w};
#pragma unroll
    for (int q = 0; q < 4; ++q) {
      union { unsigned u; float f; } lo, hi;
      lo.u = w[q] << 16;
      hi.u = w[q] & 0xffff0000u;
      s += lo.f + hi.f;
    }
  }
#pragma unroll
  for (int off = 1; off < 64; off <<= 1) s += __shfl_xor(s, off);
  if (lane == 0) rowsum[row] = s;
}

// ---- GEMM2: out = (E @ W^T)/rowsum + bias; 128x128 tile, 2x2 of 32x32 ----
__global__ __launch_bounds__(256, 3)
void gemm2_out(const u16* __restrict__ Ebf, const u16* __restrict__ Wbf,
               const float* __restrict__ rowsum, const float* __restrict__ bias,
               float* __restrict__ out) {
  constexpr int Kd = CC;
  __shared__ __align__(16) char smem[32768];

  const int t = threadIdx.x;
  const int lane = t & 63;
  const int wave = t >> 6;
  const int wr = wave >> 1, wc = wave & 1;
  const int l31 = lane & 31, khalf = lane >> 5;

  const int rowBase = blockIdx.y * 128;
  const int colBase = blockIdx.x * 128;

  f32x16 acc[2][2];
#pragma unroll
  for (int i = 0; i < 2; ++i)
#pragma unroll
    for (int j = 0; j < 2; ++j) acc[i][j] = 0.f;

  const int sr = t >> 3;
  const int fstage = ((t >> 3) & 7) ^ (((t >> 6) & 3) << 1);
  const int srcChunkOff = ((t & 7) ^ fstage) * 8;
  const u16* gA0 = Ebf + (size_t)(rowBase + sr) * Kd + srcChunkOff;
  const u16* gB0 = Wbf + (size_t)(colBase + sr) * Kd + srcChunkOff;
  const int fv = (l31 & 7) ^ (((l31 >> 3) & 3) << 1);

  for (int kc = 0; kc < Kd; kc += 64) {
#pragma unroll
    for (int it = 0; it < 4; ++it) {
      const u16* ga = gA0 + (size_t)(32 * it) * Kd + kc;
      __builtin_amdgcn_global_load_lds((gvp_t)ga, (lvp_t)(smem + it * 4096 + t * 16), 16, 0, 0);
    }
#pragma unroll
    for (int it = 0; it < 4; ++it) {
      const u16* gb = gB0 + (size_t)(32 * it) * Kd + kc;
      __builtin_amdgcn_global_load_lds((gvp_t)gb, (lvp_t)(smem + 16384 + it * 4096 + t * 16), 16, 0, 0);
    }
    __syncthreads();
#pragma unroll
    for (int ks = 0; ks < 4; ++ks) {
      const int slot = ((ks * 2 + khalf) ^ fv) * 16;
      bf16x8 af2[2], bfr2[2];
#pragma unroll
      for (int i = 0; i < 2; ++i) {
        int r = wr * 64 + i * 32 + l31;
        af2[i] = *(const bf16x8*)(smem + r * 128 + slot);
      }
#pragma unroll
      for (int j = 0; j < 2; ++j) {
        int r = wc * 64 + j * 32 + l31;
        bfr2[j] = *(const bf16x8*)(smem + 16384 + r * 128 + slot);
      }
#pragma unroll
      for (int j = 0; j < 2; ++j)
#pragma unroll
        for (int i = 0; i < 2; ++i)
          acc[i][j] = __builtin_amdgcn_mfma_f32_32x32x16_bf16(af2[i], bfr2[j], acc[i][j], 0, 0, 0);
    }
    __syncthreads();
  }

  const int rbase = rowBase + wr * 64 + 4 * khalf;
  const int cbase = colBase + wc * 64;
  int gcol[2];
  float bv[2];
#pragma unroll
  for (int j = 0; j < 2; ++j) {
    gcol[j] = cbase + j * 32 + l31;
    bv[j] = (gcol[j] < KK) ? bias[gcol[j]] : 0.f;
  }
#pragma unroll
  for (int i = 0; i < 2; ++i) {
#pragma unroll
    for (int reg = 0; reg < 16; ++reg) {
      int grow = rbase + i * 32 + (reg & 3) + 8 * (reg >> 2);
      float inv = 1.0f / rowsum[grow];
#pragma unroll
      for (int j = 0; j < 2; ++j) {
        if (gcol[j] < KK)
          out[(size_t)grow * KK + gcol[j]] = acc[i][j][reg] * inv + bv[j];
      }
    }
  }
}

// ---- workspace layout (bytes) ----
#define OFF_XB 0u                    // 8192*2048*2 = 33554432
#define OFF_CB 33554432u             // 4096*2048*2 = 16777216
#define OFF_WB 50331648u             // 1024*4096*2 = 8388608
#define OFF_EB 58720256u             // 8192*4096*2 = 67108864
#define OFF_X2 125829120u            // 8192*4
#define OFF_C2 125861888u            // 4096*4
#define OFF_RS 125878272u            // 8192*4

extern "C" void kernel_launch(void* const* d_in, const int* in_sizes, int n_in,
                              void* d_out, int out_size, void* d_ws, size_t ws_size,
                              hipStream_t stream) {
  const float* x = (const float*)d_in[0];
  const float* cen = (const float*)d_in[1];
  const float* beta = (const float*)d_in[2];
  const float* W = (const float*)d_in[3];
  const float* bias = (const float*)d_in[4];
  float* out = (float*)d_out;
  char* ws = (char*)d_ws;

  u16* xb = (u16*)(ws + OFF_XB);
  u16* cb = (u16*)(ws + OFF_CB);
  u16* wb = (u16*)(ws + OFF_WB);
  u16* eb = (u16*)(ws + OFF_EB);
  float* x2 = (float*)(ws + OFF_X2);
  float* c2 = (float*)(ws + OFF_C2);
  float* rowsum = (float*)(ws + OFF_RS);

  prep_norm_cast<<<BB + CC, 256, 0, stream>>>(x, cen, xb, cb, x2, c2);
  prep_wcast<<<KP, 256, 0, stream>>>(W, wb);
  gemm1_rbf<<<dim3(CC / 256, BB / 256), 512, 0, stream>>>(xb, cb, x2, c2, beta, eb);
  rowsum_k<<<BB / 4, 256, 0, stream>>>(eb, rowsum);
  gemm2_out<<<dim3(KP / 128, BB / 128), 256, 0, stream>>>(eb, wb, rowsum, bias, out);
}